// Round 4
// baseline (1752.752 us; speedup 1.0000x reference)
//
#include <hip/hip_runtime.h>
#include <hip/hip_cooperative_groups.h>

namespace cg = cooperative_groups;

typedef _Float16 f16;
typedef _Float16 f16x8 __attribute__((ext_vector_type(8)));
typedef float f32x16 __attribute__((ext_vector_type(16)));

#define TM 128   // block M tile
#define TN 256   // block N tile
#define BK 64

__device__ __forceinline__ void async_cp16(const void* g, void* l) {
  __builtin_amdgcn_global_load_lds(
      (const __attribute__((address_space(1))) void*)g,
      (__attribute__((address_space(3))) void*)l, 16, 0, 0);
}

// ---------------- shared device bodies (R3-proven, unchanged) -------------

// C = A @ Bt^T tile (mt,nt). Block 128x256, 4 waves of 64x128.
// LNA: 0 = A f16 via global_load_lds; 2 = A fp32, reg-staged cvt.
// EPI: 0 = bias+relu, 1 = raw write.
template <int LNA, int EPI>
__device__ __forceinline__ void gemm_tile_body(
    f16 (&sA)[TM][BK], f16 (&sB)[TN][BK], const f16* __restrict__ Af16,
    const float* __restrict__ Af32, const f16* __restrict__ Bt,
    const float* __restrict__ bias, f16* __restrict__ C, int mt, int nt,
    int N, int K) {
  const int tid = threadIdx.x;
  const int lane = tid & 63;
  const int wave = tid >> 6;
  const long long bm = (long long)mt * TM;
  const long long bn = (long long)nt * TN;
  const int wm = (wave & 1) * 64;
  const int wn = (wave >> 1) * 128;
  const int l31 = lane & 31;
  const int half = lane >> 5;

  const f16* const Abase = (LNA == 0) ? Af16 + bm * (long long)K : nullptr;
  const float* const A32base = (LNA == 2) ? Af32 + bm * (long long)K : nullptr;
  const f16* const Bbase = Bt + bn * (long long)K;
  int aOff[4], bOff[8];
#pragma unroll
  for (int i = 0; i < 4; ++i) {
    const int chunk = wave * 256 + i * 64 + lane;
    const int ml = chunk >> 3;
    const int kc = (chunk & 7) ^ (ml & 7);  // R2-verified XOR swizzle
    aOff[i] = ml * K + kc * 8;
  }
#pragma unroll
  for (int i = 0; i < 8; ++i) {
    const int chunk = wave * 512 + i * 64 + lane;
    const int ml = chunk >> 3;
    const int kc = (chunk & 7) ^ (ml & 7);
    bOff[i] = ml * K + kc * 8;
  }

  f32x16 acc[2][4] = {};  // 2(m) x 4(n) of 32x32 tiles

  const int kIters = K / BK;
  for (int kt = 0; kt < kIters; ++kt) {
    const int k0 = kt * BK;
    if (LNA == 0) {
#pragma unroll
      for (int i = 0; i < 4; ++i)
        async_cp16(Abase + aOff[i] + k0, &sA[0][0] + (wave * 256 + i * 64) * 8);
    } else {  // LNA == 2: fp32 -> f16 cvt staging
#pragma unroll
      for (int i = 0; i < 4; ++i) {
        float xv[8];
        *(float4*)(xv) = *(const float4*)(A32base + aOff[i] + k0);
        *(float4*)(xv + 4) = *(const float4*)(A32base + aOff[i] + k0 + 4);
        f16x8 o;
#pragma unroll
        for (int e = 0; e < 8; ++e) o[e] = (f16)xv[e];
        *(f16x8*)(&sA[0][0] + (wave * 256 + i * 64 + lane) * 8) = o;
      }
    }
#pragma unroll
    for (int i = 0; i < 8; ++i)
      async_cp16(Bbase + bOff[i] + k0, &sB[0][0] + (wave * 512 + i * 64) * 8);
    __syncthreads();

#pragma unroll
    for (int s = 0; s < 4; ++s) {  // K=16 per step
      const int csw = ((s * 2 + half) ^ (lane & 7)) * 8;
      f16x8 af[2], bf[4];
#pragma unroll
      for (int i = 0; i < 2; ++i) af[i] = *(const f16x8*)&sA[wm + i * 32 + l31][csw];
#pragma unroll
      for (int j = 0; j < 4; ++j) bf[j] = *(const f16x8*)&sB[wn + j * 32 + l31][csw];
#pragma unroll
      for (int i = 0; i < 2; ++i)
#pragma unroll
        for (int j = 0; j < 4; ++j)
          acc[i][j] = __builtin_amdgcn_mfma_f32_32x32x16_f16(af[i], bf[j],
                                                             acc[i][j], 0, 0, 0);
    }
    __syncthreads();
  }

  // Epilogue. 32x32 C/D: col = lane&31, row = (reg&3) + 8*(reg>>2) + 4*(lane>>5)
#pragma unroll
  for (int i = 0; i < 2; ++i)
#pragma unroll
    for (int j = 0; j < 4; ++j) {
      const long long colg = bn + wn + j * 32 + l31;
      float bval = 0.f;
      if (EPI == 0) bval = bias[colg];
#pragma unroll
      for (int reg = 0; reg < 16; ++reg) {
        const long long rowg =
            bm + wm + i * 32 + (reg & 3) + 8 * (reg >> 2) + 4 * half;
        float v = acc[i][j][reg];
        if (EPI == 0) v = fmaxf(v + bval, 0.f);
        C[rowg * N + colg] = (f16)v;
      }
    }
}

// 2048-tile id -> (mt, nt) XCD-aware remap (R0-proven, bijective).
__device__ __forceinline__ void tile_remap(int id, int& mt, int& nt) {
  nt = (id >> 3) & 3;
  mt = (id & 7) * 64 + (id >> 5);
}

// One wave: LayerNorm(row of Y) * g + b, relu, write f16 row of H.
__device__ __forceinline__ void ln_row_body(const f16* __restrict__ y,
                                            const float* __restrict__ g,
                                            const float* __restrict__ b,
                                            f16* __restrict__ h, int lane) {
  float x[16];
  float s1 = 0.f, s2 = 0.f;
#pragma unroll
  for (int p = 0; p < 2; ++p) {
    f16x8 v = *(const f16x8*)(y + p * 512 + lane * 8);
#pragma unroll
    for (int e = 0; e < 8; ++e) {
      const float f = (float)v[e];
      x[p * 8 + e] = f;
      s1 += f;
      s2 += f * f;
    }
  }
#pragma unroll
  for (int off = 32; off >= 1; off >>= 1) {
    s1 += __shfl_xor(s1, off);
    s2 += __shfl_xor(s2, off);
  }
  const float mean = s1 * (1.f / 1024.f);
  const float var = fmaxf(s2 * (1.f / 1024.f) - mean * mean, 0.f);
  const float inv = rsqrtf(var + 1e-6f);
#pragma unroll
  for (int p = 0; p < 2; ++p) {
    f16x8 o;
#pragma unroll
    for (int e = 0; e < 8; ++e) {
      const int c = p * 512 + lane * 8 + e;
      const float v = (x[p * 8 + e] - mean) * inv * g[c] + b[c];
      o[e] = (f16)fmaxf(v, 0.f);
    }
    *(f16x8*)(h + p * 512 + lane * 8) = o;
  }
}

// One wave: out = relu(dot(relu(LN(y)*g+b), Wout) + bout)
__device__ __forceinline__ void ln_out_row_body(
    const f16* __restrict__ y, const float* __restrict__ g,
    const float* __restrict__ b, const float* __restrict__ Wout,
    const float* __restrict__ bout, float* __restrict__ outp, int lane) {
  float x[16];
  float s1 = 0.f, s2 = 0.f;
#pragma unroll
  for (int p = 0; p < 2; ++p) {
    f16x8 v = *(const f16x8*)(y + p * 512 + lane * 8);
#pragma unroll
    for (int e = 0; e < 8; ++e) {
      const float f = (float)v[e];
      x[p * 8 + e] = f;
      s1 += f;
      s2 += f * f;
    }
  }
#pragma unroll
  for (int off = 32; off >= 1; off >>= 1) {
    s1 += __shfl_xor(s1, off);
    s2 += __shfl_xor(s2, off);
  }
  const float mean = s1 * (1.f / 1024.f);
  const float var = fmaxf(s2 * (1.f / 1024.f) - mean * mean, 0.f);
  const float inv = rsqrtf(var + 1e-6f);
  float dot = 0.f;
#pragma unroll
  for (int p = 0; p < 2; ++p) {
#pragma unroll
    for (int e = 0; e < 8; ++e) {
      const int c = p * 512 + lane * 8 + e;
      const float v = fmaxf((x[p * 8 + e] - mean) * inv * g[c] + b[c], 0.f);
      dot += v * Wout[c];
    }
  }
#pragma unroll
  for (int off = 32; off >= 1; off >>= 1) dot += __shfl_xor(dot, off);
  if (lane == 0) *outp = fmaxf(dot + bout[0], 0.f);
}

// W [K][1024] fp32 -> Wt [1024][K] f16, one 64x64 tile. No early return
// (cooperative phases must keep all threads converged).
__device__ __forceinline__ void transpose_body(const float* __restrict__ W,
                                               f16* __restrict__ Wt, int K,
                                               int bx, int by,
                                               float (&tile)[64][65]) {
  const int bk = by * 64;
  const int bn = bx * 64;
  const int tx = threadIdx.x & 63;
  const int ty = threadIdx.x >> 6;
  const bool act = bk < K;
  if (act) {
#pragma unroll
    for (int i = 0; i < 64; i += 4)
      tile[ty + i][tx] = W[(long long)(bk + ty + i) * 1024 + bn + tx];
  }
  __syncthreads();
  if (act) {
#pragma unroll
    for (int i = 0; i < 64; i += 4)
      Wt[(long long)(bn + ty + i) * K + bk + tx] = (f16)tile[tx][ty + i];
  }
}

// ---------------- cooperative mega-kernel -------------------------------

union MegaSM {
  struct {
    alignas(16) f16 A[TM][BK];
    alignas(16) f16 B[TN][BK];
  } g;                     // 48 KB
  float tr[64][65];        // 16.6 KB
};

__global__ __launch_bounds__(256, 2) void fused_net(
    const float* __restrict__ desc, const float* __restrict__ W0,
    const float* __restrict__ b0, const float* __restrict__ W1,
    const float* __restrict__ g1, const float* __restrict__ be1,
    const float* __restrict__ W2, const float* __restrict__ g2,
    const float* __restrict__ be2, const float* __restrict__ W3,
    const float* __restrict__ g3, const float* __restrict__ be3,
    const float* __restrict__ Wout, const float* __restrict__ bout,
    f16* __restrict__ Wt0, f16* __restrict__ Wt1, f16* __restrict__ Wt2,
    f16* __restrict__ Wt3, f16* __restrict__ H, f16* __restrict__ Y,
    float* __restrict__ out) {
  __shared__ MegaSM sm;
  cg::grid_group grid = cg::this_grid();
  const int bid = blockIdx.x;
  const int lane = threadIdx.x & 63;
  const int wave = threadIdx.x >> 6;

  // Phase 0: weight transposes (1024 virtual tiles; z=0 has K=512).
  for (int t = bid; t < 1024; t += 512) {
    const int z = t >> 8, rem = t & 255, by = rem >> 4, bx = rem & 15;
    const float* Ws = z == 0 ? W0 : (z == 1 ? W1 : (z == 2 ? W2 : W3));
    f16* Wd = z == 0 ? Wt0 : (z == 1 ? Wt1 : (z == 2 ? Wt2 : Wt3));
    transpose_body(Ws, Wd, z == 0 ? 512 : 1024, bx, by, sm.tr);
    __syncthreads();
  }
  __threadfence();
  grid.sync();

  // Phase 1: L0 = relu(desc @ W0 + b0) -> H  (fp32 cvt fused in staging)
  for (int t = bid; t < 2048; t += 512) {
    int mt, nt;
    tile_remap(t, mt, nt);
    gemm_tile_body<2, 0>(sm.g.A, sm.g.B, nullptr, desc, Wt0, b0, H, mt, nt,
                         1024, 512);
  }
  __threadfence();
  grid.sync();

  // Phase 2: L1 = H @ W1 -> Y
  for (int t = bid; t < 2048; t += 512) {
    int mt, nt;
    tile_remap(t, mt, nt);
    gemm_tile_body<0, 1>(sm.g.A, sm.g.B, H, nullptr, Wt1, nullptr, Y, mt, nt,
                         1024, 1024);
  }
  __threadfence();
  grid.sync();

  // Phase 3: ln1: H = relu(LN(Y)*g1+be1)
  for (int rb = bid; rb < 16384; rb += 512) {
    const long long row = (long long)rb * 4 + wave;
    ln_row_body(Y + row * 1024, g1, be1, H + row * 1024, lane);
  }
  __threadfence();
  grid.sync();

  // Phase 4: L2 = H @ W2 -> Y
  for (int t = bid; t < 2048; t += 512) {
    int mt, nt;
    tile_remap(t, mt, nt);
    gemm_tile_body<0, 1>(sm.g.A, sm.g.B, H, nullptr, Wt2, nullptr, Y, mt, nt,
                         1024, 1024);
  }
  __threadfence();
  grid.sync();

  // Phase 5: ln2: H = relu(LN(Y)*g2+be2)
  for (int rb = bid; rb < 16384; rb += 512) {
    const long long row = (long long)rb * 4 + wave;
    ln_row_body(Y + row * 1024, g2, be2, H + row * 1024, lane);
  }
  __threadfence();
  grid.sync();

  // Phase 6: L3 = H @ W3 -> Y
  for (int t = bid; t < 2048; t += 512) {
    int mt, nt;
    tile_remap(t, mt, nt);
    gemm_tile_body<0, 1>(sm.g.A, sm.g.B, H, nullptr, Wt3, nullptr, Y, mt, nt,
                         1024, 1024);
  }
  __threadfence();
  grid.sync();

  // Phase 7: out = relu(relu(LN(Y)*g3+be3) @ Wout + bout)
  for (int rb = bid; rb < 16384; rb += 512) {
    const long long row = (long long)rb * 4 + wave;
    ln_out_row_body(Y + row * 1024, g3, be3, Wout, bout, out + row, lane);
  }
}

// ---------------- standalone fallback kernels (R3-proven path) ----------

template <int LNA, int EPI>
__global__ __launch_bounds__(256, 2) void gemm_f16(
    const f16* __restrict__ Af16, const float* __restrict__ Af32,
    const f16* __restrict__ Bt, const float* __restrict__ bias,
    f16* __restrict__ C, int M, int N, int K) {
  __shared__ alignas(16) f16 sA[TM][BK];
  __shared__ alignas(16) f16 sB[TN][BK];
  int mt, nt;
  if (gridDim.x == 4 && gridDim.y == 512) {
    const int id = blockIdx.y * 4 + blockIdx.x;
    tile_remap(id, mt, nt);
  } else {
    nt = blockIdx.x;
    mt = blockIdx.y;
  }
  gemm_tile_body<LNA, EPI>(sA, sB, Af16, Af32, Bt, bias, C, mt, nt, N, K);
}

__global__ __launch_bounds__(256) void ln_relu_kernel(
    const f16* __restrict__ Y, const float* __restrict__ g,
    const float* __restrict__ b, f16* __restrict__ H) {
  const int lane = threadIdx.x & 63;
  const int wave = threadIdx.x >> 6;
  const long long row = (long long)blockIdx.x * 4 + wave;
  ln_row_body(Y + row * 1024, g, b, H + row * 1024, lane);
}

__global__ __launch_bounds__(256) void ln_relu_out_kernel(
    const f16* __restrict__ Y, const float* __restrict__ g,
    const float* __restrict__ b, const float* __restrict__ Wout,
    const float* __restrict__ bout, float* __restrict__ out) {
  const int lane = threadIdx.x & 63;
  const int wave = threadIdx.x >> 6;
  const long long row = (long long)blockIdx.x * 4 + wave;
  ln_out_row_body(Y + row * 1024, g, b, Wout, bout, out + row, lane);
}

__global__ __launch_bounds__(256) void transpose_cvt_all(
    const float* __restrict__ W0, const float* __restrict__ W1,
    const float* __restrict__ W2, const float* __restrict__ W3,
    f16* __restrict__ Wt0, f16* __restrict__ Wt1, f16* __restrict__ Wt2,
    f16* __restrict__ Wt3) {
  __shared__ float tile[64][65];
  const int z = blockIdx.z;
  const float* W = z == 0 ? W0 : (z == 1 ? W1 : (z == 2 ? W2 : W3));
  f16* Wt = z == 0 ? Wt0 : (z == 1 ? Wt1 : (z == 2 ? Wt2 : Wt3));
  transpose_body(W, Wt, z == 0 ? 512 : 1024, blockIdx.x, blockIdx.y, tile);
}

extern "C" void kernel_launch(void* const* d_in, const int* in_sizes, int n_in,
                              void* d_out, int out_size, void* d_ws, size_t ws_size,
                              hipStream_t stream) {
  const float* desc = (const float*)d_in[0];
  const float* W0 = (const float*)d_in[1];
  const float* b0 = (const float*)d_in[2];
  const float* W1 = (const float*)d_in[3];
  const float* g1 = (const float*)d_in[4];
  const float* be1 = (const float*)d_in[5];
  const float* W2 = (const float*)d_in[6];
  const float* g2 = (const float*)d_in[7];
  const float* be2 = (const float*)d_in[8];
  const float* W3 = (const float*)d_in[9];
  const float* g3 = (const float*)d_in[10];
  const float* be3 = (const float*)d_in[11];
  const float* Wout = (const float*)d_in[12];
  const float* bout = (const float*)d_in[13];
  float* out = (float*)d_out;

  const long long Nrows = 65536, D = 512, W = 1024;
  char* p = (char*)d_ws;
  f16* Wt0 = (f16*)p;   p += D * W * sizeof(f16);       // 1 MB
  f16* Wt1 = (f16*)p;   p += W * W * sizeof(f16);       // 2 MB
  f16* Wt2 = (f16*)p;   p += W * W * sizeof(f16);       // 2 MB
  f16* Wt3 = (f16*)p;   p += W * W * sizeof(f16);       // 2 MB
  f16* H = (f16*)p;     p += Nrows * W * sizeof(f16);   // 134.2 MB
  f16* Y = (f16*)p;     p += Nrows * W * sizeof(f16);   // 134.2 MB
  (void)ws_size; (void)in_sizes; (void)n_in; (void)out_size;

  void* kargs[] = {&desc, &W0, &b0, &W1, &g1, &be1, &W2, &g2, &be2,
                   &W3, &g3, &be3, &Wout, &bout, &Wt0, &Wt1, &Wt2, &Wt3,
                   &H, &Y, &out};
  const hipError_t err = hipLaunchCooperativeKernel(
      reinterpret_cast<void*>(fused_net), dim3(512), dim3(256), kargs, 0,
      stream);
  if (err == hipSuccess) return;

  // Fallback: R3-proven multi-launch path.
  transpose_cvt_all<<<dim3(16, 16, 4), 256, 0, stream>>>(W0, W1, W2, W3, Wt0,
                                                         Wt1, Wt2, Wt3);
  dim3 ggrid(W / TN, Nrows / TM);  // (4, 512)
  gemm_f16<2, 0><<<ggrid, 256, 0, stream>>>(nullptr, desc, Wt0, b0, H,
                                            (int)Nrows, (int)W, (int)D);
  gemm_f16<0, 1><<<ggrid, 256, 0, stream>>>(H, nullptr, Wt1, nullptr, Y,
                                            (int)Nrows, (int)W, (int)W);
  ln_relu_kernel<<<(int)(Nrows / 4), 256, 0, stream>>>(Y, g1, be1, H);
  gemm_f16<0, 1><<<ggrid, 256, 0, stream>>>(H, nullptr, Wt2, nullptr, Y,
                                            (int)Nrows, (int)W, (int)W);
  ln_relu_kernel<<<(int)(Nrows / 4), 256, 0, stream>>>(Y, g2, be2, H);
  gemm_f16<0, 1><<<ggrid, 256, 0, stream>>>(H, nullptr, Wt3, nullptr, Y,
                                            (int)Nrows, (int)W, (int)W);
  ln_relu_out_kernel<<<(int)(Nrows / 4), 256, 0, stream>>>(Y, g3, be3, Wout,
                                                           bout, out);
}

// Round 5
// 851.355 us; speedup vs baseline: 2.0588x; 2.0588x over previous
//
#include <hip/hip_runtime.h>

typedef _Float16 f16;
typedef _Float16 f16x8 __attribute__((ext_vector_type(8)));
typedef float f32x16 __attribute__((ext_vector_type(16)));

#define TM 128   // block M tile
#define TN 256   // block N tile
#define BK 64

__device__ __forceinline__ void async_cp16(const void* g, void* l) {
  __builtin_amdgcn_global_load_lds(
      (const __attribute__((address_space(1))) void*)g,
      (__attribute__((address_space(3))) void*)l, 16, 0, 0);
}

// C = A @ Bt^T, A [M][K] f16/f32, Bt [N][K] f16 row-major.
// Block 128x256, 4 waves of 64x128 (2x4 of 32x32 MFMA accs). R0-proven
// structure at the m97-class ceiling (~808 TF, MfmaUtil 36%). Structural
// variants all regressed and are reverted: 8-phase 256^2 (R1: 1 blk/CU
// lost inter-block overlap at nT=16), LN-in-A-staging (R2: serial reg-
// staging latency), cooperative mega-kernel (R4: lockstep phases + fence
// L2 flush halved every pipe). This IS the plateau of this structure.
// LNA: 0 = A f16 via global_load_lds (async, fastest); 2 = A fp32,
//      reg-staged cvt (R2-measured ~free for GEMM0).
// NOTE: SQ_LDS_BANK_CONFLICT saturates at 2^24 -- do not trust it.
template <int LNA, int EPI>
__global__ __launch_bounds__(256, 2) void gemm_f16(
    const f16* __restrict__ Af16, const float* __restrict__ Af32,
    const f16* __restrict__ Bt, const float* __restrict__ bias,
    f16* __restrict__ C, int M, int N, int K) {
  __shared__ alignas(16) f16 sA[TM][BK];
  __shared__ alignas(16) f16 sB[TN][BK];
  const int tid = threadIdx.x;
  const int lane = tid & 63;
  const int wave = tid >> 6;

  // XCD-aware remap: the 4 blocks sharing an A-panel (same mt) get ids
  // spaced 8 apart -> same XCD under round-robin dispatch -> panel stays
  // in that XCD's L2. (R2-verified mechanism: FETCH 530 -> 112 MB.)
  int mt, nt;
  if (gridDim.x == 4 && gridDim.y == 512) {
    const int id = blockIdx.y * 4 + blockIdx.x;
    nt = (id >> 3) & 3;
    mt = (id & 7) * 64 + (id >> 5);
  } else {
    nt = blockIdx.x;
    mt = blockIdx.y;
  }
  const long long bm = (long long)mt * TM;
  const long long bn = (long long)nt * TN;

  const int wm = (wave & 1) * 64;    // wave's 64-row band
  const int wn = (wave >> 1) * 128;  // wave's 128-col band
  const int l31 = lane & 31;
  const int half = lane >> 5;

  // Block-uniform bases (SGPR) + 32-bit lane-dependent element offsets.
  const f16* const Abase = Af16 + bm * (long long)K;
  const float* const A32base = Af32 ? (Af32 + bm * (long long)K) : nullptr;
  const f16* const Bbase = Bt + bn * (long long)K;
  int aOff[4], bOff[8];
#pragma unroll
  for (int i = 0; i < 4; ++i) {
    const int chunk = wave * 256 + i * 64 + lane;
    const int ml = chunk >> 3;
    const int kc = (chunk & 7) ^ (ml & 7);  // R2-verified XOR swizzle
    aOff[i] = ml * K + kc * 8;
  }
#pragma unroll
  for (int i = 0; i < 8; ++i) {
    const int chunk = wave * 512 + i * 64 + lane;
    const int ml = chunk >> 3;
    const int kc = (chunk & 7) ^ (ml & 7);
    bOff[i] = ml * K + kc * 8;
  }

  f32x16 acc[2][4] = {};  // 2(m) x 4(n) of 32x32 tiles

  const int kIters = K / BK;
  for (int kt = 0; kt < kIters; ++kt) {
    const int k0 = kt * BK;
    if (LNA == 0) {
#pragma unroll
      for (int i = 0; i < 4; ++i)
        async_cp16(Abase + aOff[i] + k0, &sA[0][0] + (wave * 256 + i * 64) * 8);
    } else {  // LNA == 2: fp32 -> f16 cvt staging (GEMM0 only)
#pragma unroll
      for (int i = 0; i < 4; ++i) {
        float xv[8];
        *(float4*)(xv) = *(const float4*)(A32base + aOff[i] + k0);
        *(float4*)(xv + 4) = *(const float4*)(A32base + aOff[i] + k0 + 4);
        f16x8 o;
#pragma unroll
        for (int e = 0; e < 8; ++e) o[e] = (f16)xv[e];
        *(f16x8*)(&sA[0][0] + (wave * 256 + i * 64 + lane) * 8) = o;
      }
    }
#pragma unroll
    for (int i = 0; i < 8; ++i)
      async_cp16(Bbase + bOff[i] + k0, &sB[0][0] + (wave * 512 + i * 64) * 8);
    __syncthreads();

#pragma unroll
    for (int s = 0; s < 4; ++s) {  // K=16 per step
      // A-operand 32x32x16: m = lane&31, k = (lane>>5)*8 + j (B mirrors, n).
      const int csw = ((s * 2 + half) ^ (lane & 7)) * 8;
      f16x8 af[2], bf[4];
#pragma unroll
      for (int i = 0; i < 2; ++i) af[i] = *(const f16x8*)&sA[wm + i * 32 + l31][csw];
#pragma unroll
      for (int j = 0; j < 4; ++j) bf[j] = *(const f16x8*)&sB[wn + j * 32 + l31][csw];
#pragma unroll
      for (int i = 0; i < 2; ++i)
#pragma unroll
        for (int j = 0; j < 4; ++j)
          acc[i][j] = __builtin_amdgcn_mfma_f32_32x32x16_f16(af[i], bf[j],
                                                             acc[i][j], 0, 0, 0);
    }
    __syncthreads();
  }

  // Epilogue. 32x32 C/D: col = lane&31, row = (reg&3) + 8*(reg>>2) + 4*(lane>>5)
#pragma unroll
  for (int i = 0; i < 2; ++i)
#pragma unroll
    for (int j = 0; j < 4; ++j) {
      const long long colg = bn + wn + j * 32 + l31;
      float bval = 0.f;
      if (EPI == 0) bval = bias[colg];
#pragma unroll
      for (int reg = 0; reg < 16; ++reg) {
        const long long rowg =
            bm + wm + i * 32 + (reg & 3) + 8 * (reg >> 2) + 4 * half;
        float v = acc[i][j][reg];
        if (EPI == 0) v = fmaxf(v + bval, 0.f);
        C[rowg * N + colg] = (f16)v;
      }
    }
}

// One wave per row: LayerNorm(y) * g + b, relu, write f16. (R2-proven.)
__global__ __launch_bounds__(256) void ln_relu_kernel(
    const f16* __restrict__ Y, const float* __restrict__ g,
    const float* __restrict__ b, f16* __restrict__ H) {
  const int lane = threadIdx.x & 63;
  const int wave = threadIdx.x >> 6;
  const long long row = (long long)blockIdx.x * 4 + wave;
  const f16* y = Y + row * 1024;
  float x[16];
  float s1 = 0.f, s2 = 0.f;
#pragma unroll
  for (int p = 0; p < 2; ++p) {
    f16x8 v = *(const f16x8*)(y + p * 512 + lane * 8);
#pragma unroll
    for (int e = 0; e < 8; ++e) {
      const float f = (float)v[e];
      x[p * 8 + e] = f;
      s1 += f;
      s2 += f * f;
    }
  }
#pragma unroll
  for (int off = 32; off >= 1; off >>= 1) {
    s1 += __shfl_xor(s1, off);
    s2 += __shfl_xor(s2, off);
  }
  const float mean = s1 * (1.f / 1024.f);
  const float var = fmaxf(s2 * (1.f / 1024.f) - mean * mean, 0.f);
  const float inv = rsqrtf(var + 1e-6f);
  f16* h = H + row * 1024;
#pragma unroll
  for (int p = 0; p < 2; ++p) {
    f16x8 o;
#pragma unroll
    for (int e = 0; e < 8; ++e) {
      const int c = p * 512 + lane * 8 + e;
      const float v = (x[p * 8 + e] - mean) * inv * g[c] + b[c];
      o[e] = (f16)fmaxf(v, 0.f);
    }
    *(f16x8*)(h + p * 512 + lane * 8) = o;
  }
}

// Fused layer-3 LN + relu + output dot (R2-proven):
// out[row] = relu(dot(relu(LN(y)*g+b), Wout) + bout)
__global__ __launch_bounds__(256) void ln_relu_out_kernel(
    const f16* __restrict__ Y, const float* __restrict__ g,
    const float* __restrict__ b, const float* __restrict__ Wout,
    const float* __restrict__ bout, float* __restrict__ out) {
  const int lane = threadIdx.x & 63;
  const int wave = threadIdx.x >> 6;
  const long long row = (long long)blockIdx.x * 4 + wave;
  const f16* y = Y + row * 1024;
  float x[16];
  float s1 = 0.f, s2 = 0.f;
#pragma unroll
  for (int p = 0; p < 2; ++p) {
    f16x8 v = *(const f16x8*)(y + p * 512 + lane * 8);
#pragma unroll
    for (int e = 0; e < 8; ++e) {
      const float f = (float)v[e];
      x[p * 8 + e] = f;
      s1 += f;
      s2 += f * f;
    }
  }
#pragma unroll
  for (int off = 32; off >= 1; off >>= 1) {
    s1 += __shfl_xor(s1, off);
    s2 += __shfl_xor(s2, off);
  }
  const float mean = s1 * (1.f / 1024.f);
  const float var = fmaxf(s2 * (1.f / 1024.f) - mean * mean, 0.f);
  const float inv = rsqrtf(var + 1e-6f);
  float dot = 0.f;
#pragma unroll
  for (int p = 0; p < 2; ++p) {
#pragma unroll
    for (int e = 0; e < 8; ++e) {
      const int c = p * 512 + lane * 8 + e;
      const float v = fmaxf((x[p * 8 + e] - mean) * inv * g[c] + b[c], 0.f);
      dot += v * Wout[c];
    }
  }
#pragma unroll
  for (int off = 32; off >= 1; off >>= 1) dot += __shfl_xor(dot, off);
  if (lane == 0) out[row] = fmaxf(dot + bout[0], 0.f);
}

// All 4 weight transposes in ONE launch. z selects the matrix.
// W [K][N] fp32 -> Wt [N][K] f16, 64x64 LDS tiles. N = 1024 for all;
// K = 512 for z=0 (half the y-tiles return early).
__global__ __launch_bounds__(256) void transpose_cvt_all(
    const float* __restrict__ W0, const float* __restrict__ W1,
    const float* __restrict__ W2, const float* __restrict__ W3,
    f16* __restrict__ Wt0, f16* __restrict__ Wt1, f16* __restrict__ Wt2,
    f16* __restrict__ Wt3) {
  const int z = blockIdx.z;
  const float* W = z == 0 ? W0 : (z == 1 ? W1 : (z == 2 ? W2 : W3));
  f16* Wt = z == 0 ? Wt0 : (z == 1 ? Wt1 : (z == 2 ? Wt2 : Wt3));
  const int K = z == 0 ? 512 : 1024;
  const int N = 1024;
  const int bk = blockIdx.y * 64;
  if (bk >= K) return;
  __shared__ float tile[64][65];
  const int bn = blockIdx.x * 64;
  const int tx = threadIdx.x & 63;
  const int ty = threadIdx.x >> 6;  // 0..3
#pragma unroll
  for (int i = 0; i < 64; i += 4)
    tile[ty + i][tx] = W[(long long)(bk + ty + i) * N + bn + tx];
  __syncthreads();
#pragma unroll
  for (int i = 0; i < 64; i += 4)
    Wt[(long long)(bn + ty + i) * K + bk + tx] = (f16)tile[tx][ty + i];
}

extern "C" void kernel_launch(void* const* d_in, const int* in_sizes, int n_in,
                              void* d_out, int out_size, void* d_ws, size_t ws_size,
                              hipStream_t stream) {
  const float* desc = (const float*)d_in[0];
  const float* W0 = (const float*)d_in[1];
  const float* b0 = (const float*)d_in[2];
  const float* W1 = (const float*)d_in[3];
  const float* g1 = (const float*)d_in[4];
  const float* be1 = (const float*)d_in[5];
  const float* W2 = (const float*)d_in[6];
  const float* g2 = (const float*)d_in[7];
  const float* be2 = (const float*)d_in[8];
  const float* W3 = (const float*)d_in[9];
  const float* g3 = (const float*)d_in[10];
  const float* be3 = (const float*)d_in[11];
  const float* Wout = (const float*)d_in[12];
  const float* bout = (const float*)d_in[13];
  float* out = (float*)d_out;

  const long long Nrows = 65536, D = 512, W = 1024;
  char* p = (char*)d_ws;
  f16* Wt0 = (f16*)p;   p += D * W * sizeof(f16);       // 1 MB
  f16* Wt1 = (f16*)p;   p += W * W * sizeof(f16);       // 2 MB
  f16* Wt2 = (f16*)p;   p += W * W * sizeof(f16);       // 2 MB
  f16* Wt3 = (f16*)p;   p += W * W * sizeof(f16);       // 2 MB
  f16* H = (f16*)p;     p += Nrows * W * sizeof(f16);   // 134.2 MB
  f16* Y = (f16*)p;     p += Nrows * W * sizeof(f16);   // 134.2 MB
  (void)ws_size; (void)in_sizes; (void)n_in; (void)out_size;

  transpose_cvt_all<<<dim3(16, 16, 4), 256, 0, stream>>>(W0, W1, W2, W3, Wt0,
                                                         Wt1, Wt2, Wt3);

  dim3 ggrid(W / TN, Nrows / TM);  // (4, 512)

  // L0: relu(desc @ W0 + b0) -> H   (fp32 cvt fused into A-staging)
  gemm_f16<2, 0><<<ggrid, 256, 0, stream>>>(nullptr, desc, Wt0, b0, H,
                                            (int)Nrows, (int)W, (int)D);

  // L1: H @ W1 -> Y
  gemm_f16<0, 1><<<ggrid, 256, 0, stream>>>(H, nullptr, Wt1, nullptr, Y,
                                            (int)Nrows, (int)W, (int)W);
  ln_relu_kernel<<<(int)(Nrows / 4), 256, 0, stream>>>(Y, g1, be1, H);

  // L2
  gemm_f16<0, 1><<<ggrid, 256, 0, stream>>>(H, nullptr, Wt2, nullptr, Y,
                                            (int)Nrows, (int)W, (int)W);
  ln_relu_kernel<<<(int)(Nrows / 4), 256, 0, stream>>>(Y, g2, be2, H);

  // L3
  gemm_f16<0, 1><<<ggrid, 256, 0, stream>>>(H, nullptr, Wt3, nullptr, Y,
                                            (int)Nrows, (int)W, (int)W);

  // out = relu(relu(LN3(Y)) @ Wout + bout)
  ln_relu_out_kernel<<<(int)(Nrows / 4), 256, 0, stream>>>(Y, g3, be3, Wout,
                                                           bout, out);
}